// Round 1
// baseline (1012.203 us; speedup 1.0000x reference)
//
#include <hip/hip_runtime.h>
#include <stdint.h>

// BinaryDense: out[N,128] = inputs[N,128] @ w_bin[128,128], w_bin = ±1 from
// JAX threefry-partitionable bernoulli(hard_sigmoid(weight)).
//
// PRNG H1 (verified passing, absmax 0.25): partitionable threefry —
//   bits[i] = o0 ^ o1 where (o0,o1) = threefry2x32(key=(0,seed), x0=0, x1=i)
//
// This round: operand-swap MFMA (W as first operand -> lane holds 4
// consecutive output cols -> dwordx4 stores) + cross-strip software
// prefetch of A + persistent grid (1024 = resident capacity).

typedef _Float16 half8 __attribute__((ext_vector_type(8)));
typedef float f32x4 __attribute__((ext_vector_type(4)));

__device__ __forceinline__ uint32_t rotl32(uint32_t x, int n) {
    return (x << n) | (x >> (32 - n));
}

__device__ __forceinline__ void threefry2x32(uint32_t k0, uint32_t k1,
                                             uint32_t x0, uint32_t x1,
                                             uint32_t& o0, uint32_t& o1) {
    const uint32_t ks0 = k0, ks1 = k1, ks2 = 0x1BD11BDAu ^ k0 ^ k1;
    x0 += ks0; x1 += ks1;
#define TF_ROUND(r) { x0 += x1; x1 = rotl32(x1, (r)); x1 ^= x0; }
    TF_ROUND(13) TF_ROUND(15) TF_ROUND(26) TF_ROUND(6)
    x0 += ks1; x1 += ks2 + 1u;
    TF_ROUND(17) TF_ROUND(29) TF_ROUND(16) TF_ROUND(24)
    x0 += ks2; x1 += ks0 + 2u;
    TF_ROUND(13) TF_ROUND(15) TF_ROUND(26) TF_ROUND(6)
    x0 += ks0; x1 += ks1 + 3u;
    TF_ROUND(17) TF_ROUND(29) TF_ROUND(16) TF_ROUND(24)
    x0 += ks1; x1 += ks2 + 4u;
    TF_ROUND(13) TF_ROUND(15) TF_ROUND(26) TF_ROUND(6)
    x0 += ks2; x1 += ks0 + 5u;
#undef TF_ROUND
    o0 = x0; o1 = x1;
}

// Kernel 1: binarize weight -> f16 (+1/-1) in MFMA fragment order.
// Weight flat index i = k*128 + n  (k in D, n in F).
// Fragment addr (used as FIRST mfma operand, row=n): tile=n>>4, kstep=k>>5,
// q=(k>>3)&3, j=k&7, lane=q*16+(n&15) -> frag[((tile*4+kstep)*64+lane)*8 + j]
// (identical mapping to the previous B-operand layout — per-lane A/B layouts
// coincide for 16x16x32.)
__global__ void binarize_kernel(const float* __restrict__ weight,
                                const int* __restrict__ seed_p,
                                const int* __restrict__ train_p,
                                unsigned short* __restrict__ bfrag) {
    const int i = blockIdx.x * 256 + threadIdx.x;  // 0..16383
    const uint32_t seed_lo = (uint32_t)(*seed_p);  // jax key = (hi=0, lo=seed)
    const int training = *train_p;
    const float w = weight[i];

    unsigned short sign_bits;
    if (training) {
        uint32_t o0, o1;
        threefry2x32(0u, seed_lo, 0u, (uint32_t)i, o0, o1);
        const uint32_t bits = o0 ^ o1;  // partitionable 32-bit fold
        const float u = __uint_as_float((bits >> 9) | 0x3F800000u) - 1.0f;
        float p = (w + 1.0f) * 0.5f;
        p = fminf(fmaxf(p, 0.0f), 1.0f);
        sign_bits = (u < p) ? 0x3C00u : 0xBC00u;  // f16 +1 : -1
    } else {
        sign_bits = (w > 0.0f) ? 0x3C00u : 0xBC00u;
    }

    const int k = i >> 7, n = i & 127;
    const int tile = n >> 4, kstep = k >> 5, q = (k >> 3) & 3, j = k & 7;
    const int lane = q * 16 + (n & 15);
    bfrag[((tile * 4 + kstep) * 64 + lane) * 8 + j] = sign_bits;
}

// Kernel 2: tall-skinny GEMM, operand-swapped MFMA.
// D = W^T(frag as A-operand) * A^T(frag as B-operand) -> lane holds
// out[base+ (lane&15)][tile*16 + (lane>>4)*4 + reg] -> float4 stores that
// fill complete 64B lines per instruction (lanes l, l+16, l+32, l+48).
__global__ __launch_bounds__(256, 4)
void gemm_bin_kernel(const float* __restrict__ A,
                     const unsigned short* __restrict__ bfrag,
                     float* __restrict__ out,
                     int nstrips) {
    __shared__ unsigned short ldsB[16384];  // 32 KB: all W fragments
    {
        const uint4* src = (const uint4*)bfrag;
        uint4* dst = (uint4*)ldsB;
        const int t = threadIdx.x;
#pragma unroll
        for (int i = 0; i < 8; ++i) dst[t + i * 256] = src[t + i * 256];
    }

    const int lane = threadIdx.x & 63;
    const int wv = threadIdx.x >> 6;
    const int m = lane & 15;   // A row within wave tile (= output row)
    const int q = lane >> 4;   // quad: k-group for loads, col-group for stores

    int s = (int)blockIdx.x;
    const int sstep = (int)gridDim.x;

    // Prologue: issue first strip's loads before the barrier (independent of LDS).
    float4 fbuf[8];
    if (s < nstrips) {
        const float* arow = A + ((int64_t)s * 64 + wv * 16 + m) * 128 + q * 8;
#pragma unroll
        for (int kk = 0; kk < 4; ++kk) {
            fbuf[2 * kk]     = *(const float4*)(arow + kk * 32);
            fbuf[2 * kk + 1] = *(const float4*)(arow + kk * 32 + 4);
        }
    }
    __syncthreads();

    while (s < nstrips) {
        // Convert current strip's A to f16 fragments (frees fbuf).
        half8 afr[4];
#pragma unroll
        for (int kk = 0; kk < 4; ++kk) {
            afr[kk][0] = (_Float16)fbuf[2 * kk].x;
            afr[kk][1] = (_Float16)fbuf[2 * kk].y;
            afr[kk][2] = (_Float16)fbuf[2 * kk].z;
            afr[kk][3] = (_Float16)fbuf[2 * kk].w;
            afr[kk][4] = (_Float16)fbuf[2 * kk + 1].x;
            afr[kk][5] = (_Float16)fbuf[2 * kk + 1].y;
            afr[kk][6] = (_Float16)fbuf[2 * kk + 1].z;
            afr[kk][7] = (_Float16)fbuf[2 * kk + 1].w;
        }

        // Software prefetch: next strip's loads fly under the MFMA+store phase.
        const int snext = s + sstep;
        if (snext < nstrips) {
            const float* arow = A + ((int64_t)snext * 64 + wv * 16 + m) * 128 + q * 8;
#pragma unroll
            for (int kk = 0; kk < 4; ++kk) {
                fbuf[2 * kk]     = *(const float4*)(arow + kk * 32);
                fbuf[2 * kk + 1] = *(const float4*)(arow + kk * 32 + 4);
            }
        }

        float* orow = out + ((int64_t)s * 64 + wv * 16 + m) * 128 + q * 4;
#pragma unroll
        for (int tt = 0; tt < 8; ++tt) {
            f32x4 acc = {0.f, 0.f, 0.f, 0.f};
#pragma unroll
            for (int kk = 0; kk < 4; ++kk) {
                const half8 wfr = *(const half8*)(&ldsB[((tt * 4 + kk) * 64 + lane) * 8]);
                // Swapped operands: W-frag first, A-frag second.
                acc = __builtin_amdgcn_mfma_f32_16x16x32_f16(wfr, afr[kk], acc, 0, 0, 0);
            }
            // D layout (col=lane&15=row m, row=q*4+reg=out col) -> contiguous 16B.
            float4 o;
            o.x = acc[0]; o.y = acc[1]; o.z = acc[2]; o.w = acc[3];
            *(float4*)(orow + tt * 16) = o;
        }
        s = snext;
    }
}

extern "C" void kernel_launch(void* const* d_in, const int* in_sizes, int n_in,
                              void* d_out, int out_size, void* d_ws, size_t ws_size,
                              hipStream_t stream) {
    const float* A = (const float*)d_in[0];       // [N,128] fp32
    const float* W = (const float*)d_in[1];       // [128,128] fp32
    const int* seed = (const int*)d_in[2];
    const int* train = (const int*)d_in[3];
    float* out = (float*)d_out;
    unsigned short* bfrag = (unsigned short*)d_ws;  // 16384 f16 = 32 KB

    const int N = in_sizes[0] / 128;
    const int nstrips = N / 64;

    binarize_kernel<<<64, 256, 0, stream>>>(W, seed, train, bfrag);

    // Persistent-resident grid: 4 blocks/CU x 256 CU = 1024; 16 strips/block
    // keeps the cross-strip prefetch pipeline warm.
    int grid = 1024;
    if (grid > nstrips) grid = nstrips;
    gemm_bin_kernel<<<grid, 256, 0, stream>>>(A, bfrag, out, nstrips);
}